// Round 1
// baseline (380.140 us; speedup 1.0000x reference)
//
#include <hip/hip_runtime.h>

#define D_ 1024
#define H_ 16
#define DK_ 64
#define S_ 1024
#define B_ 4

typedef __attribute__((ext_vector_type(4))) float f32x4;
typedef __attribute__((ext_vector_type(8))) short bf16x8;
typedef __attribute__((ext_vector_type(4))) unsigned int u32x4;

__device__ __forceinline__ unsigned short f2bf(float f) {
  unsigned u = __builtin_bit_cast(unsigned, f);
  u += 0x7FFFu + ((u >> 16) & 1u);
  return (unsigned short)(u >> 16);
}

__device__ __forceinline__ bf16x8 ldg8(const unsigned short* p) {
  return __builtin_bit_cast(bf16x8, *reinterpret_cast<const u32x4*>(p));
}

__device__ __forceinline__ f32x4 mfma16(bf16x8 a, bf16x8 b, f32x4 c) {
  return __builtin_amdgcn_mfma_f32_16x16x32_bf16(a, b, c, 0, 0, 0);
}

// ---------------- fp32 -> bf16 conversion (inputs + weights) ----------------
struct CvtJobs {
  const float* src[7];
  unsigned short* dst[7];
  int n4[7];
};

__global__ void k_convert(CvtJobs jobs) {
  const int j = blockIdx.y;
  const float* __restrict__ s = jobs.src[j];
  unsigned short* __restrict__ d = jobs.dst[j];
  const int n4 = jobs.n4[j];
  const int stride = gridDim.x * blockDim.x;
  for (int i = blockIdx.x * blockDim.x + threadIdx.x; i < n4; i += stride) {
    float4 v = reinterpret_cast<const float4*>(s)[i];
    unsigned long long pk =
        (unsigned long long)f2bf(v.x) |
        ((unsigned long long)f2bf(v.y) << 16) |
        ((unsigned long long)f2bf(v.z) << 32) |
        ((unsigned long long)f2bf(v.w) << 48);
    reinterpret_cast<unsigned long long*>(d)[i] = pk;
  }
}

// ---------------- generic NT GEMM: C[m,n] = (sum_k A[m,k]*B[n,k] + bias[n])*scale
// M=N=K=1024 fixed, grid (8,8,B). MODE 0: ->qh/kh bf16 [B,H,S,DK]; MODE 1: ->vT bf16 [B,H,DK,S];
// MODE 2: -> d_out fp32 (S,B,D). AF32: A operand is fp32 (converted during staging).
template <int MODE, int AF32>
__global__ __launch_bounds__(256) void k_gemm(
    const void* __restrict__ Ap, int lda, long azs,
    const unsigned short* __restrict__ Bp,
    const float* __restrict__ bias,
    void* __restrict__ Cp, float scale)
{
  __shared__ unsigned short As[128 * 40];
  __shared__ unsigned short Bs[128 * 40];
  const int tid = threadIdx.x;
  const int lane = tid & 63;
  const int w = tid >> 6;
  const int wm = (w >> 1) * 64;
  const int wn = (w & 1) * 64;
  const int m0 = blockIdx.y * 128;
  const int n0 = blockIdx.x * 128;
  const int bz = blockIdx.z;
  const int srow = tid >> 1;
  const int shalf = tid & 1;
  const int l15 = lane & 15;
  const int lg = lane >> 4;

  f32x4 acc[4][4] = {};

  for (int kt = 0; kt < 32; ++kt) {
    if (AF32) {
      const float* ga = (const float*)Ap + (long)bz * azs + (long)(m0 + srow) * lda + kt * 32 + shalf * 16;
      unsigned* dst = reinterpret_cast<unsigned*>(&As[srow * 40 + shalf * 16]);
      #pragma unroll
      for (int i = 0; i < 8; ++i) {
        float a0 = ga[2 * i], a1 = ga[2 * i + 1];
        dst[i] = (unsigned)f2bf(a0) | ((unsigned)f2bf(a1) << 16);
      }
    } else {
      const unsigned short* ga = (const unsigned short*)Ap + (long)bz * azs + (long)(m0 + srow) * lda + kt * 32 + shalf * 16;
      u32x4 av0 = *reinterpret_cast<const u32x4*>(ga);
      u32x4 av1 = *reinterpret_cast<const u32x4*>(ga + 8);
      *reinterpret_cast<u32x4*>(&As[srow * 40 + shalf * 16]) = av0;
      *reinterpret_cast<u32x4*>(&As[srow * 40 + shalf * 16 + 8]) = av1;
    }
    {
      const unsigned short* gb = Bp + (long)(n0 + srow) * 1024 + kt * 32 + shalf * 16;
      u32x4 bv0 = *reinterpret_cast<const u32x4*>(gb);
      u32x4 bv1 = *reinterpret_cast<const u32x4*>(gb + 8);
      *reinterpret_cast<u32x4*>(&Bs[srow * 40 + shalf * 16]) = bv0;
      *reinterpret_cast<u32x4*>(&Bs[srow * 40 + shalf * 16 + 8]) = bv1;
    }
    __syncthreads();
    bf16x8 af[4], bfr[4];
    #pragma unroll
    for (int i = 0; i < 4; ++i)
      af[i] = __builtin_bit_cast(bf16x8, *reinterpret_cast<const u32x4*>(&As[(wm + i * 16 + l15) * 40 + lg * 8]));
    #pragma unroll
    for (int i = 0; i < 4; ++i)
      bfr[i] = __builtin_bit_cast(bf16x8, *reinterpret_cast<const u32x4*>(&Bs[(wn + i * 16 + l15) * 40 + lg * 8]));
    #pragma unroll
    for (int mf = 0; mf < 4; ++mf)
      #pragma unroll
      for (int nf = 0; nf < 4; ++nf)
        acc[mf][nf] = mfma16(af[mf], bfr[nf], acc[mf][nf]);
    __syncthreads();
  }

  #pragma unroll
  for (int nf = 0; nf < 4; ++nf) {
    const int gc = n0 + wn + nf * 16 + l15;
    const float bv = bias[gc];
    #pragma unroll
    for (int mf = 0; mf < 4; ++mf) {
      #pragma unroll
      for (int r = 0; r < 4; ++r) {
        const int gr = m0 + wm + mf * 16 + lg * 4 + r;
        float v = (acc[mf][nf][r] + bv) * scale;
        if (MODE == 0) {
          ((unsigned short*)Cp)[(((long)bz * H_ + (gc >> 6)) * S_ + gr) * DK_ + (gc & 63)] = f2bf(v);
        } else if (MODE == 1) {
          ((unsigned short*)Cp)[(((long)bz * H_ + (gc >> 6)) * DK_ + (gc & 63)) * S_ + gr] = f2bf(v);
        } else {
          ((float*)Cp)[(long)gr * (B_ * D_) + (long)bz * D_ + gc] = v;
        }
      }
    }
  }
}

// ---------------- fused attention: scores -> softmax -> head-mix -> LN -> PV
// grid (S/16, B), 1024 threads = 16 waves; wave w = head w; Q-tile = 16 rows.
__global__ __launch_bounds__(1024) void k_attn(
    const unsigned short* __restrict__ qh,
    const unsigned short* __restrict__ kh,
    const unsigned short* __restrict__ vT,
    const float* __restrict__ head_att,
    const float* __restrict__ ln_g,
    const float* __restrict__ ln_b,
    float* __restrict__ Ym,
    float* __restrict__ att_out)
{
  __shared__ float p32[H_ * 1040];   // fp32 probs [h][q*65+kc], padded; reused as bf16 attn2 planes
  __shared__ float haS[256];
  __shared__ float lngS[16];
  __shared__ float lnbS[16];
  const int tid = threadIdx.x;
  const int lane = tid & 63;
  const int w = tid >> 6;
  const int l15 = lane & 15;
  const int lg = lane >> 4;
  const int b = blockIdx.y;
  const int q0 = blockIdx.x * 16;

  if (tid < 256) haS[tid] = head_att[tid];
  if (tid < 16) { lngS[tid] = ln_g[tid]; lnbS[tid] = ln_b[tid]; }

  // Q fragments in registers (q already pre-scaled by 1/8 in projection)
  const long hq = ((long)(b * H_ + w) * S_ + q0 + l15) * DK_ + lg * 8;
  bf16x8 qf0 = ldg8(qh + hq);
  bf16x8 qf1 = ldg8(qh + hq + 32);
  const unsigned short* kbase = kh + (long)(b * H_ + w) * S_ * DK_;
  const unsigned short* vbase = vT + (long)(b * H_ + w) * DK_ * S_;

  float m[4], l[4];
  #pragma unroll
  for (int r = 0; r < 4; ++r) { m[r] = -3.0e38f; l[r] = 0.0f; }

  // ---- pass 1: online softmax stats (m, l) ----
  for (int kt = 0; kt < 16; ++kt) {
    f32x4 sa[4] = {};
    #pragma unroll
    for (int nf = 0; nf < 4; ++nf) {
      const unsigned short* kp = kbase + (long)(kt * 64 + nf * 16 + l15) * DK_ + lg * 8;
      sa[nf] = mfma16(qf0, ldg8(kp), sa[nf]);
      sa[nf] = mfma16(qf1, ldg8(kp + 32), sa[nf]);
    }
    #pragma unroll
    for (int r = 0; r < 4; ++r) {
      float tm = fmaxf(fmaxf(sa[0][r], sa[1][r]), fmaxf(sa[2][r], sa[3][r]));
      tm = fmaxf(tm, __shfl_xor(tm, 1));
      tm = fmaxf(tm, __shfl_xor(tm, 2));
      tm = fmaxf(tm, __shfl_xor(tm, 4));
      tm = fmaxf(tm, __shfl_xor(tm, 8));
      const float mn = fmaxf(m[r], tm);
      float ps = __expf(sa[0][r] - mn) + __expf(sa[1][r] - mn) +
                 __expf(sa[2][r] - mn) + __expf(sa[3][r] - mn);
      ps += __shfl_xor(ps, 1);
      ps += __shfl_xor(ps, 2);
      ps += __shfl_xor(ps, 4);
      ps += __shfl_xor(ps, 8);
      l[r] = l[r] * __expf(m[r] - mn) + ps;
      m[r] = mn;
    }
  }
  float invl[4];
  #pragma unroll
  for (int r = 0; r < 4; ++r) invl[r] = 1.0f / l[r];

  // ---- pass 2: p -> mix -> LN -> attn2(bf16, XOR-swizzled LDS) -> PV ----
  f32x4 yacc[4] = {};
  char* pbc = reinterpret_cast<char*>(p32);

  for (int kt = 0; kt < 16; ++kt) {
    f32x4 sa[4] = {};
    #pragma unroll
    for (int nf = 0; nf < 4; ++nf) {
      const unsigned short* kp = kbase + (long)(kt * 64 + nf * 16 + l15) * DK_ + lg * 8;
      sa[nf] = mfma16(qf0, ldg8(kp), sa[nf]);
      sa[nf] = mfma16(qf1, ldg8(kp + 32), sa[nf]);
    }
    #pragma unroll
    for (int nf = 0; nf < 4; ++nf)
      #pragma unroll
      for (int r = 0; r < 4; ++r) {
        float p = __expf(sa[nf][r] - m[r]) * invl[r];
        p32[w * 1040 + (lg * 4 + r) * 65 + nf * 16 + l15] = p;
      }
    __syncthreads();

    // mix + layernorm; thread owns position (q = w, kc = lane)
    float ph[16];
    #pragma unroll
    for (int h = 0; h < 16; ++h) ph[h] = p32[h * 1040 + w * 65 + lane];
    float mx[16];
    #pragma unroll
    for (int g = 0; g < 16; ++g) mx[g] = 0.0f;
    #pragma unroll
    for (int h = 0; h < 16; ++h) {
      const float p = ph[h];
      #pragma unroll
      for (int g4 = 0; g4 < 4; ++g4) {
        const float4 hv = reinterpret_cast<const float4*>(&haS[h * 16])[g4];
        mx[g4 * 4 + 0] += p * hv.x;
        mx[g4 * 4 + 1] += p * hv.y;
        mx[g4 * 4 + 2] += p * hv.z;
        mx[g4 * 4 + 3] += p * hv.w;
      }
    }
    float mean = 0.0f;
    #pragma unroll
    for (int g = 0; g < 16; ++g) mean += mx[g];
    mean *= 0.0625f;
    float var = 0.0f;
    #pragma unroll
    for (int g = 0; g < 16; ++g) { const float dd = mx[g] - mean; var += dd * dd; }
    var *= 0.0625f;
    const float rs = rsqrtf(var + 1e-5f);
    __syncthreads();  // all p32 reads complete before aliased bf16 writes

    float am = 0.0f;
    #pragma unroll
    for (int g = 0; g < 16; ++g) {
      const float o = (mx[g] - mean) * rs * lngS[g] + lnbS[g];
      am += o;
      unsigned bo = (unsigned)(g * 4096 + w * 128 + lane * 2);
      bo ^= (unsigned)((w & 7) << 4);
      *reinterpret_cast<unsigned short*>(pbc + bo) = f2bf(o);
    }
    att_out[(long)b * S_ * S_ + (long)(q0 + w) * S_ + kt * 64 + lane] = am * 0.0625f;
    __syncthreads();

    // PV: A = attn2 plane w (swizzled read), B = vT rows (global)
    bf16x8 pa0, pa1;
    {
      const unsigned ub = (unsigned)(w * 4096 + l15 * 128 + lg * 16);
      const unsigned swz = (unsigned)((l15 & 7) << 4);
      pa0 = __builtin_bit_cast(bf16x8, *reinterpret_cast<const u32x4*>(pbc + (ub ^ swz)));
      pa1 = __builtin_bit_cast(bf16x8, *reinterpret_cast<const u32x4*>(pbc + ((ub + 64) ^ swz)));
    }
    #pragma unroll
    for (int nf = 0; nf < 4; ++nf) {
      const unsigned short* vp = vbase + (long)(nf * 16 + l15) * S_ + kt * 64 + lg * 8;
      yacc[nf] = mfma16(pa0, ldg8(vp), yacc[nf]);
      yacc[nf] = mfma16(pa1, ldg8(vp + 32), yacc[nf]);
    }
    __syncthreads();  // PV reads done before next iter's p32 writes
  }

  // epilogue: merged-head Y (fp32) [B,S,D]
  #pragma unroll
  for (int nf = 0; nf < 4; ++nf)
    #pragma unroll
    for (int r = 0; r < 4; ++r)
      Ym[((long)b * S_ + q0 + lg * 4 + r) * D_ + w * 64 + nf * 16 + l15] = yacc[nf][r];
}

extern "C" void kernel_launch(void* const* d_in, const int* in_sizes, int n_in,
                              void* d_out, int out_size, void* d_ws, size_t ws_size,
                              hipStream_t stream) {
  const float* q_in = (const float*)d_in[0];
  const float* k_in = (const float*)d_in[1];
  const float* v_in = (const float*)d_in[2];
  const float* Wq = (const float*)d_in[3];
  const float* bq = (const float*)d_in[4];
  const float* Wk = (const float*)d_in[5];
  const float* bk = (const float*)d_in[6];
  const float* Wv = (const float*)d_in[7];
  const float* bv = (const float*)d_in[8];
  const float* Wo = (const float*)d_in[9];
  const float* bo = (const float*)d_in[10];
  const float* head_att = (const float*)d_in[11];
  const float* ln_g = (const float*)d_in[12];
  const float* ln_b = (const float*)d_in[13];

  char* ws = (char*)d_ws;
  unsigned short* xq = (unsigned short*)(ws);
  unsigned short* xk = (unsigned short*)(ws + 8388608);
  unsigned short* xv = (unsigned short*)(ws + 16777216);
  unsigned short* Wqb = (unsigned short*)(ws + 25165824);
  unsigned short* Wkb = (unsigned short*)(ws + 27262976);
  unsigned short* Wvb = (unsigned short*)(ws + 29360128);
  unsigned short* Wob = (unsigned short*)(ws + 31457280);
  unsigned short* qhp = (unsigned short*)(ws + 33554432);
  unsigned short* khp = (unsigned short*)(ws + 41943040);
  unsigned short* vTp = (unsigned short*)(ws + 50331648);
  float* Ym = (float*)(ws + 58720256);  // 16 MB, ends at 72 MB

  CvtJobs cj;
  cj.src[0] = q_in; cj.dst[0] = xq;  cj.n4[0] = 1048576;
  cj.src[1] = k_in; cj.dst[1] = xk;  cj.n4[1] = 1048576;
  cj.src[2] = v_in; cj.dst[2] = xv;  cj.n4[2] = 1048576;
  cj.src[3] = Wq;   cj.dst[3] = Wqb; cj.n4[3] = 262144;
  cj.src[4] = Wk;   cj.dst[4] = Wkb; cj.n4[4] = 262144;
  cj.src[5] = Wv;   cj.dst[5] = Wvb; cj.n4[5] = 262144;
  cj.src[6] = Wo;   cj.dst[6] = Wob; cj.n4[6] = 262144;
  k_convert<<<dim3(512, 7), 256, 0, stream>>>(cj);

  dim3 gg(8, 8, 4);
  // q projection pre-scaled by 1/sqrt(dk) = 0.125
  k_gemm<0, 0><<<gg, 256, 0, stream>>>(xq, 4096, 1024L, Wqb, bq, qhp, 0.125f);
  k_gemm<0, 0><<<gg, 256, 0, stream>>>(xk, 4096, 1024L, Wkb, bk, khp, 1.0f);
  k_gemm<1, 0><<<gg, 256, 0, stream>>>(xv, 4096, 1024L, Wvb, bv, vTp, 1.0f);

  k_attn<<<dim3(64, 4), 1024, 0, stream>>>(qhp, khp, vTp, head_att, ln_g, ln_b,
                                           Ym, (float*)d_out + (long)S_ * B_ * D_);

  k_gemm<2, 1><<<gg, 256, 0, stream>>>(Ym, 1024, 1048576L, Wob, bo, d_out, 1.0f);
}